// Round 5
// baseline (269.701 us; speedup 1.0000x reference)
//
#include <hip/hip_runtime.h>

// AdEx neuron simulation: B=32, T=2000, D=1024. Bitwise-exact vs JAX/XLA:CPU
// (numerics proven R3/R4: Cephes exp + FMA-contracted step, absmax 0.0).
//
// R5 = parallel-in-time. Hot regime (a=b=0, R=1, Delta_T pow2): state is 1-D V;
// spikes reset V to the CONSTANT V_reset -> state collapses at spikes.
// Split T into NC chunks; each chunk (c>0) runs a WARM-step conservative
// interval-hull warmup [lo,hi] containing the true V:
//   flo=f(lo), fhi=f(hi)  (f = exact bitwise step, monotone up to ulp glitches)
//   flo >= Vs+0.01  -> ALL states spike -> hull collapses to {V_reset}: EXACT.
//   fhi <  Vs-0.01  -> NO state spikes -> hull narrows (inflated +-0.004/step).
//   else straddle   -> hull = [min(Vr, flo-SL), nextbelow(Vs)].
// Margins/inflation make every claim conservative: a wrong guess can only
// DELAY collapse (-> flag -> serial fixup), never produce a silent error.
// After collapse the chunk simulates its 400 steps exactly (R4 hot loop).
// Kernel 2 fixes flagged (neuron,chunk) serially from saved exact boundary
// states (expected zero work). ws too small / non-hot params -> R4 serial.

#define Bn 32
#define Tn 2000
#define Dn 1024
#define NEUR (Bn * Dn)       // 32768
#define UNR 16
#define NC 5
#define CHK 400              // steps per chunk (NC*CHK == Tn)
#define WARM 160             // warmup steps (multiple of UNR)
#define CBLK (CHK / UNR)     // 25
#define WBLK (WARM / UNR)    // 10
#define FBLK (Tn / UNR)      // 125 (serial fallback)
#define BPC (NEUR / 128)     // 256 blocks per chunk

// ---------- exp: XLA:CPU / Eigen Cephes, FMA-contracted (R3-proven) ----------
#define EXP_LOG2EF 1.44269504088896341f
#define EXP_C1 0.693359375f
#define EXP_C2 -2.12194440e-4f
#define EXP_P0 1.9875691500e-4f
#define EXP_P1 1.3981999507e-3f
#define EXP_P2 8.3334519073e-3f
#define EXP_P3 4.1665795894e-2f
#define EXP_P4 1.6666665459e-1f
#define EXP_P5 5.0000001201e-1f

__device__ __forceinline__ float ref_expf(float x) {
    #pragma clang fp contract(off)
    float fx = __builtin_floorf(__builtin_fmaf(x, EXP_LOG2EF, 0.5f));
    float xr = __builtin_fmaf(fx, -EXP_C1, x);
    xr = __builtin_fmaf(fx, -EXP_C2, xr);
    float z2 = xr * xr;
    float y = EXP_P0;
    y = __builtin_fmaf(y, xr, EXP_P1);
    y = __builtin_fmaf(y, xr, EXP_P2);
    y = __builtin_fmaf(y, xr, EXP_P3);
    y = __builtin_fmaf(y, xr, EXP_P4);
    y = __builtin_fmaf(y, xr, EXP_P5);
    y = __builtin_fmaf(y, z2, xr);
    y = y + 1.0f;
    const int n = (int)fx;
    return y * __int_as_float((n + 127) << 23);
}

// exp(x) * 2^kdt -- folds Delta_T (pow2) into the exact scale. Bitwise == DT*exp(x).
__device__ __forceinline__ float expsc(float x, int kdt) {
    #pragma clang fp contract(off)
    float fx = __builtin_floorf(__builtin_fmaf(x, EXP_LOG2EF, 0.5f));
    float xr = __builtin_fmaf(fx, -EXP_C1, x);
    xr = __builtin_fmaf(fx, -EXP_C2, xr);
    float z2 = xr * xr;
    float y = EXP_P0;
    y = __builtin_fmaf(y, xr, EXP_P1);
    y = __builtin_fmaf(y, xr, EXP_P2);
    y = __builtin_fmaf(y, xr, EXP_P3);
    y = __builtin_fmaf(y, xr, EXP_P4);
    y = __builtin_fmaf(y, xr, EXP_P5);
    y = __builtin_fmaf(y, z2, xr);
    y = y + 1.0f;
    const int n = (int)fx;
    return y * __int_as_float((n + 127 + kdt) << 23);
}

// Markstein correctly-rounded division by loop-invariant d, r = RN(1/d).
__device__ __forceinline__ float mark_div(float x, float d, float r) {
    #pragma clang fp contract(off)
    float q = x * r;
    float e = __builtin_fmaf(-d, q, x);
    return __builtin_fmaf(e, r, q);
}

struct HP {
    float tau_m, E_L, V_T, rDT, rTM, dt, Vs, Vrst, xC, nC;
    int kdt;
};

// One exact hot step (R4-proven bitwise). Carried state (V, x, nEL).
__device__ __forceinline__ bool hot_step(float& V, float& x, float& nEL,
                                         float i_t, const HP p) {
    #pragma clang fp contract(off)
    const float et = expsc(x, p.kdt);
    float nm = nEL + et;
    nm = nm + i_t;
    const float dV = mark_div(nm, p.tau_m, p.rTM);
    const float Vp = __builtin_fmaf(p.dt, dV, V);
    const bool s = (Vp >= p.Vs);
    const float xn = (Vp - p.V_T) * p.rDT;
    const float nn = p.E_L - Vp;
    V   = s ? p.Vrst : Vp;
    x   = s ? p.xC : xn;
    nEL = s ? p.nC : nn;
    return s;
}

// Pre-reset image f(V) -- same ops as the carried form (bitwise-identical f).
__device__ __forceinline__ float fpre(float V, float i_t, const HP p) {
    #pragma clang fp contract(off)
    const float xx = (V - p.V_T) * p.rDT;
    const float nn = p.E_L - V;
    const float et = expsc(xx, p.kdt);
    float nm = nn + et;
    nm = nm + i_t;
    const float dV = mark_div(nm, p.tau_m, p.rTM);
    return __builtin_fmaf(p.dt, dV, V);
}

// ---------- R3-proven fallback steps (plain IEEE divides) ----------
__device__ __forceinline__ void step_simple(float& V, float i_t, float& spk_out,
                                            float E_L, float V_T, float Delta_T,
                                            float R, float tau_m, float V_spike,
                                            float V_reset, float dt) {
    #pragma clang fp contract(off)
    const float e  = ref_expf((V - V_T) / Delta_T);
    const float et = Delta_T * e;
    float nm = (-(V - E_L) + et);
    nm = nm + R * i_t;
    const float dV = nm / tau_m;
    V = __builtin_fmaf(dt, dV, V);
    spk_out = (V >= V_spike) ? 1.0f : 0.0f;
    V = (V >= V_spike) ? V_reset : V;
}

__device__ __forceinline__ void step_general(float& V, float& w, float i_t, float& spk_out,
                                             float E_L, float V_T, float Delta_T,
                                             float R, float tau_m, float tau_w,
                                             float a, float b,
                                             float V_spike, float V_reset, float dt) {
    #pragma clang fp contract(off)
    const float e  = ref_expf((V - V_T) / Delta_T);
    const float et = Delta_T * e;
    float nm = (-(V - E_L) + et);
    nm = __builtin_fmaf(-R, w, nm);
    nm = __builtin_fmaf(R, i_t, nm);
    const float dV = nm / tau_m;
    V = __builtin_fmaf(dt, dV, V);
    const float dwn = __builtin_fmaf(a, (V - E_L), -w);
    const float dw  = dwn / tau_w;
    w = __builtin_fmaf(dt, dw, w);
    spk_out = (V >= V_spike) ? 1.0f : 0.0f;
    const bool s = (V >= V_spike);
    V = s ? V_reset : V;
    w = s ? (w + b) : w;
}

// Double-buffered UNR-deep prefetch loop. __VA_ARGS__ = per-step statement;
// uses: i_t (input), OSLOT (float* output slot). IPTR/OPTR advance per block.
#define RUN_BLOCKS(IPTR, OPTR, NBLK, ...) do {                                    \
    float bufA_[UNR], bufB_[UNR];                                                 \
    _Pragma("unroll") for (int k = 0; k < UNR; ++k) bufA_[k] = (IPTR)[k * Dn];    \
    for (int tb = 0; tb < (NBLK); tb += 2) {                                      \
        if (tb + 1 < (NBLK)) {                                                    \
            const float* pp_ = (IPTR) + (size_t)(tb + 1) * (UNR * Dn);            \
            _Pragma("unroll") for (int k = 0; k < UNR; ++k) bufB_[k] = pp_[k*Dn]; \
        }                                                                         \
        {                                                                         \
            float* oo_ = (OPTR) + (size_t)tb * (UNR * Dn);                        \
            _Pragma("unroll") for (int k = 0; k < UNR; ++k) {                     \
                const float i_t = bufA_[k];                                       \
                float* OSLOT = oo_ + (size_t)k * Dn; (void)OSLOT;                 \
                __VA_ARGS__;                                                      \
            }                                                                     \
        }                                                                         \
        if (tb + 2 < (NBLK)) {                                                    \
            const float* pp_ = (IPTR) + (size_t)(tb + 2) * (UNR * Dn);            \
            _Pragma("unroll") for (int k = 0; k < UNR; ++k) bufA_[k] = pp_[k*Dn]; \
        }                                                                         \
        if (tb + 1 < (NBLK)) {                                                    \
            float* oo_ = (OPTR) + (size_t)(tb + 1) * (UNR * Dn);                  \
            _Pragma("unroll") for (int k = 0; k < UNR; ++k) {                     \
                const float i_t = bufB_[k];                                       \
                float* OSLOT = oo_ + (size_t)k * Dn; (void)OSLOT;                 \
                __VA_ARGS__;                                                      \
            }                                                                     \
        }                                                                         \
    }                                                                             \
} while (0)

__launch_bounds__(128, 1)
__global__ void adex_chunked(const float* __restrict__ I,
                             const float* __restrict__ params,
                             float* __restrict__ out,
                             int* __restrict__ flags,
                             float* __restrict__ Vend,
                             int use_chunked) {
    #pragma clang fp contract(off)
    const float tau_m   = params[0];
    const float E_L     = params[1];
    const float V_T     = params[2];
    const float Delta_T = params[3];
    const float R       = params[4];
    const float tau_w   = params[5];
    const float a       = params[6];
    const float b       = params[7];
    const float V_reset = params[8];
    const float V_spike = params[9];
    const float dt      = params[10];

    const unsigned dtBits = __float_as_uint(Delta_T);
    const bool dtPow2 = ((dtBits & 0x7FFFFFu) == 0u) && Delta_T > 0.0f;
    const bool hot = (a == 0.0f) && (b == 0.0f) && (R == 1.0f) && dtPow2;

    const int c  = use_chunked ? (int)(blockIdx.x >> 8) : 0;
    const int wb = use_chunked ? (int)(blockIdx.x & 255) : (int)blockIdx.x;
    const int n  = wb * 128 + (int)threadIdx.x;
    const int bb = n >> 10;
    const int dd = n & (Dn - 1);

    const float* Ibase = I   + (size_t)bb * (size_t)(Tn * Dn) + dd;
    float*       Obase = out + (size_t)bb * (size_t)(Tn * Dn) + dd;

    if (!hot || !use_chunked) {
        if (use_chunked) {
            flags[c * NEUR + n] = 0;       // Phase-B no-ops
            if (c > 0) return;
        }
        // ---- full serial fallback (R4-proven) ----
        float V = E_L;
        if (hot) {
            const int   kdt = (int)((dtBits >> 23) & 0xFFu) - 127;
            const float rDT = 1.0f / Delta_T;
            const float rTM = 1.0f / tau_m;
            HP p = {tau_m, E_L, V_T, rDT, rTM, dt, V_spike, V_reset,
                    (V_reset - V_T) * rDT, E_L - V_reset, kdt};
            float x = (V - V_T) * rDT, nEL = E_L - V;
            RUN_BLOCKS(Ibase, Obase, FBLK,
                { const bool s = hot_step(V, x, nEL, i_t, p); *OSLOT = s ? 1.0f : 0.0f; });
        } else if (a == 0.0f && b == 0.0f) {
            RUN_BLOCKS(Ibase, Obase, FBLK,
                { float spk; step_simple(V, i_t, spk, E_L, V_T, Delta_T, R, tau_m,
                                         V_spike, V_reset, dt); *OSLOT = spk; });
        } else {
            float w = 0.0f;
            RUN_BLOCKS(Ibase, Obase, FBLK,
                { float spk; step_general(V, w, i_t, spk, E_L, V_T, Delta_T, R, tau_m,
                                          tau_w, a, b, V_spike, V_reset, dt); *OSLOT = spk; });
        }
        return;
    }

    // ---- chunked hot path ----
    const int   kdt = (int)((dtBits >> 23) & 0xFFu) - 127;
    const float rDT = 1.0f / Delta_T;
    const float rTM = 1.0f / tau_m;
    const HP p = {tau_m, E_L, V_T, rDT, rTM, dt, V_spike, V_reset,
                  (V_reset - V_T) * rDT, E_L - V_reset, kdt};

    const float VsPM     = V_spike + 0.01f;                          // collapse margin
    const float VsMM     = V_spike - 0.01f;                          // sure-no-spike margin
    const float VsMinusC = __uint_as_float(__float_as_uint(V_spike) - 1u); // nextbelow(Vs)
    const float SL       = 0.004f;                                   // per-step hull inflation
    const float LO0      = -100.0f;                                  // data floor (see header)

    float V, x, nEL;
    bool collapsed;

    if (c == 0) {
        V = E_L; x = (V - V_T) * rDT; nEL = E_L - V;
        collapsed = true;
    } else {
        // warmup: hull [lo,hi] + exact V-chain (valid post-collapse)
        const float* Iw = Ibase + (size_t)(c * CHK - WARM) * Dn;
        float lo = LO0, hi = VsMinusC;
        V = p.Vrst; x = p.xC; nEL = p.nC;   // placeholder until collapse
        collapsed = false;
        RUN_BLOCKS(Iw, Obase, WBLK, {
            const float flo = fpre(lo, i_t, p);
            const float fhi = fpre(hi, i_t, p);
            hot_step(V, x, nEL, i_t, p);     // garbage until collapsed; bounded (real dynamics)
            if (!collapsed) {
                if (flo >= VsPM) {
                    collapsed = true; V = p.Vrst; x = p.xC; nEL = p.nC;
                } else if (fhi < VsMM) {
                    lo = flo - SL; hi = fhi + SL;
                } else {
                    lo = fminf(p.Vrst, flo - SL); hi = VsMinusC;
                }
            }
        });
    }

    // exact phase over [c*CHK, (c+1)*CHK)
    {
        const float* Ie = Ibase + (size_t)(c * CHK) * Dn;
        float*       Oe = Obase + (size_t)(c * CHK) * Dn;
        RUN_BLOCKS(Ie, Oe, CBLK,
            { const bool s = hot_step(V, x, nEL, i_t, p); *OSLOT = s ? 1.0f : 0.0f; });
    }
    Vend [c * NEUR + n] = V;                  // exact iff collapsed (or c==0)
    flags[c * NEUR + n] = collapsed ? 0 : 1;
}

__launch_bounds__(128, 1)
__global__ void adex_fixup(const float* __restrict__ I,
                           const float* __restrict__ params,
                           float* __restrict__ out,
                           const int* __restrict__ flags,
                           const float* __restrict__ Vend,
                           int use_chunked) {
    #pragma clang fp contract(off)
    if (!use_chunked) return;
    const float tau_m   = params[0];
    const float E_L     = params[1];
    const float V_T     = params[2];
    const float Delta_T = params[3];
    const float R       = params[4];
    const float a       = params[6];
    const float b       = params[7];
    const float V_reset = params[8];
    const float V_spike = params[9];
    const float dt      = params[10];

    const unsigned dtBits = __float_as_uint(Delta_T);
    const bool dtPow2 = ((dtBits & 0x7FFFFFu) == 0u) && Delta_T > 0.0f;
    const bool hot = (a == 0.0f) && (b == 0.0f) && (R == 1.0f) && dtPow2;
    if (!hot) return;                        // flags are all 0 in that mode anyway

    const int n  = (int)blockIdx.x * 128 + (int)threadIdx.x;
    const int bb = n >> 10;
    const int dd = n & (Dn - 1);

    int any = 0;
    #pragma unroll
    for (int cc = 1; cc < NC; ++cc) any |= flags[cc * NEUR + n];
    if (!any) return;                        // expected path: zero work

    const int   kdt = (int)((dtBits >> 23) & 0xFFu) - 127;
    const float rDT = 1.0f / Delta_T;
    const float rTM = 1.0f / tau_m;
    const HP p = {tau_m, E_L, V_T, rDT, rTM, dt, V_spike, V_reset,
                  (V_reset - V_T) * rDT, E_L - V_reset, kdt};

    const float* Ibase = I   + (size_t)bb * (size_t)(Tn * Dn) + dd;
    float*       Obase = out + (size_t)bb * (size_t)(Tn * Dn) + dd;

    float carry = Vend[0 * NEUR + n];        // exact state at t = CHK
    for (int cc = 1; cc < NC; ++cc) {
        const float Vst = flags[(cc - 1) * NEUR + n] ? carry : Vend[(cc - 1) * NEUR + n];
        if (flags[cc * NEUR + n]) {
            float V = Vst, x = (Vst - p.V_T) * p.rDT, nEL = p.E_L - Vst;
            const float* Ie = Ibase + (size_t)(cc * CHK) * Dn;
            float*       Oe = Obase + (size_t)(cc * CHK) * Dn;
            RUN_BLOCKS(Ie, Oe, CBLK,
                { const bool s = hot_step(V, x, nEL, i_t, p); *OSLOT = s ? 1.0f : 0.0f; });
            carry = V;
        } else {
            carry = Vend[cc * NEUR + n];
        }
    }
}

extern "C" void kernel_launch(void* const* d_in, const int* in_sizes, int n_in,
                              void* d_out, int out_size, void* d_ws, size_t ws_size,
                              hipStream_t stream) {
    const float* I      = (const float*)d_in[0];
    const float* params = (const float*)d_in[1];
    float*       out    = (float*)d_out;

    const size_t need = (size_t)NC * NEUR * 4u * 2u;   // flags + Vend = 1.31 MB
    const int use_chunked = (ws_size >= need) ? 1 : 0;
    int*   flags = (int*)d_ws;
    float* Vend  = (float*)((char*)d_ws + (size_t)NC * NEUR * 4u);

    dim3 block(128);
    dim3 grid1(use_chunked ? NC * BPC : BPC);
    adex_chunked<<<grid1, block, 0, stream>>>(I, params, out, flags, Vend, use_chunked);
    adex_fixup<<<dim3(BPC), block, 0, stream>>>(I, params, out, flags, Vend, use_chunked);
}

// Round 6
// 190.169 us; speedup vs baseline: 1.4182x; 1.4182x over previous
//
#include <hip/hip_runtime.h>

// AdEx neuron simulation: B=32, T=2000, D=1024. Bitwise-exact vs JAX/XLA:CPU
// (numerics proven R3/R4: XLA Cephes exp + FMA-contracted step, absmax 0.0).
//
// R6 = back to single-kernel serial (R5 parallel-in-time refuted: post-reset
// phase ambiguity is irreducible). Chain surgery on the carried dependency:
//   - speculative t1 select: t1 = s ? (Vrst-V_T) : (Vp-V_T); exp runs off t1,
//     no select after exp. Bitwise: select distributes over exact ops.
//   - rDT (pow2) folded into exp head: x = t1*rDT exact; fma(x,log2e,0.5)
//     == fma(t1, log2e*rDT, 0.5) bitwise (exact exponent-shift of constant).
//   - Delta_T*exp folded into 2^n scale (R4-proven), Markstein div (R4-proven),
//     V' = fma(dt,dV,V) (R3-proven), nEL select speculative (R4-proven).
// Carried chain ~20 ops: sub/sel -> exp(12) -> 2 adds -> div(3) -> fma.

#define Bn 32
#define Tn 2000
#define Dn 1024
#define NEUR (Bn * Dn)     // 32768
#define UNR 16             // prefetch depth (2000 % 16 == 0 -> NB = 125)
#define NB (Tn / UNR)

// ---------- exp: XLA:CPU / Eigen Cephes, FMA-contracted (R3-proven) ----------
#define EXP_LOG2EF 1.44269504088896341f
#define EXP_C1 0.693359375f
#define EXP_C2 -2.12194440e-4f
#define EXP_P0 1.9875691500e-4f
#define EXP_P1 1.3981999507e-3f
#define EXP_P2 8.3334519073e-3f
#define EXP_P3 4.1665795894e-2f
#define EXP_P4 1.6666665459e-1f
#define EXP_P5 5.0000001201e-1f

__device__ __forceinline__ float ref_expf(float x) {
    #pragma clang fp contract(off)
    float fx = __builtin_floorf(__builtin_fmaf(x, EXP_LOG2EF, 0.5f));
    float xr = __builtin_fmaf(fx, -EXP_C1, x);
    xr = __builtin_fmaf(fx, -EXP_C2, xr);
    float z2 = xr * xr;
    float y = EXP_P0;
    y = __builtin_fmaf(y, xr, EXP_P1);
    y = __builtin_fmaf(y, xr, EXP_P2);
    y = __builtin_fmaf(y, xr, EXP_P3);
    y = __builtin_fmaf(y, xr, EXP_P4);
    y = __builtin_fmaf(y, xr, EXP_P5);
    y = __builtin_fmaf(y, z2, xr);
    y = y + 1.0f;
    const int n = (int)fx;
    return y * __int_as_float((n + 127) << 23);
}

// Hot-path constants (all loop-invariant).
struct HP {
    float tau_m, rTM, dt, Vs, Vrst, E_L, V_T;
    float rDT;     // 1/Delta_T, exact power of 2
    float KH;      // EXP_LOG2EF * rDT, exact (exponent shift)
    float T1C;     // RN(Vrst - V_T)   (reset-branch t1)
    float nC;      // RN(E_L - Vrst)   (reset-branch nEL)
    int   kdt;     // log2(Delta_T)
};

// One exact hot step. Carried state: V, t1 = (V - V_T) [selected],
// nEL = (E_L - V) [selected]. Bitwise == R4 hot_step (proven absmax 0.0):
//   x = t1*rDT exact; fma(x,LOG2EF,.5) == fma(t1,KH,.5) bitwise;
//   xr/poly/scale identical; Delta_T folded via kdt in the scale.
__device__ __forceinline__ float hot_step(float& V, float& t1, float& nEL,
                                          float i_t, const HP p) {
    #pragma clang fp contract(off)
    const float x  = t1 * p.rDT;                                  // exact
    const float fx = __builtin_floorf(__builtin_fmaf(t1, p.KH, 0.5f));
    float xr = __builtin_fmaf(fx, -EXP_C1, x);
    xr = __builtin_fmaf(fx, -EXP_C2, xr);
    const float z2 = xr * xr;
    float y = __builtin_fmaf(EXP_P0, xr, EXP_P1);
    y = __builtin_fmaf(y, xr, EXP_P2);
    y = __builtin_fmaf(y, xr, EXP_P3);
    y = __builtin_fmaf(y, xr, EXP_P4);
    y = __builtin_fmaf(y, xr, EXP_P5);
    y = __builtin_fmaf(y, z2, xr);
    y = y + 1.0f;
    const int   nsc = (int)fx;
    const float sc  = __int_as_float((nsc + 127 + p.kdt) << 23);  // 2^(n+kdt)
    const float et  = y * sc;                                     // Delta_T*exp(x)
    float nm = nEL + et;
    nm = nm + i_t;                                                // R == 1
    const float q  = nm * p.rTM;                                  // Markstein div
    const float er = __builtin_fmaf(-p.tau_m, q, nm);
    const float dV = __builtin_fmaf(er, p.rTM, q);
    const float Vp = __builtin_fmaf(p.dt, dV, V);
    const bool  s  = (Vp >= p.Vs);
    V   = s ? p.Vrst : Vp;
    t1  = s ? p.T1C  : (Vp - p.V_T);    // speculative, constant on spike path
    nEL = s ? p.nC   : (p.E_L - Vp);    // speculative
    return s ? 1.0f : 0.0f;
}

// ---------- R3-proven fallback steps (plain IEEE divides) ----------
__device__ __forceinline__ void step_simple(float& V, float i_t, float& spk_out,
                                            float E_L, float V_T, float Delta_T,
                                            float R, float tau_m, float V_spike,
                                            float V_reset, float dt) {
    #pragma clang fp contract(off)
    const float e  = ref_expf((V - V_T) / Delta_T);
    const float et = Delta_T * e;
    float nm = (-(V - E_L) + et);
    nm = nm + R * i_t;
    const float dV = nm / tau_m;
    V = __builtin_fmaf(dt, dV, V);
    spk_out = (V >= V_spike) ? 1.0f : 0.0f;
    V = (V >= V_spike) ? V_reset : V;
}

__device__ __forceinline__ void step_general(float& V, float& w, float i_t, float& spk_out,
                                             float E_L, float V_T, float Delta_T,
                                             float R, float tau_m, float tau_w,
                                             float a, float b,
                                             float V_spike, float V_reset, float dt) {
    #pragma clang fp contract(off)
    const float e  = ref_expf((V - V_T) / Delta_T);
    const float et = Delta_T * e;
    float nm = (-(V - E_L) + et);
    nm = __builtin_fmaf(-R, w, nm);
    nm = __builtin_fmaf(R, i_t, nm);
    const float dV = nm / tau_m;
    V = __builtin_fmaf(dt, dV, V);
    const float dwn = __builtin_fmaf(a, (V - E_L), -w);
    const float dw  = dwn / tau_w;
    w = __builtin_fmaf(dt, dw, w);
    spk_out = (V >= V_spike) ? 1.0f : 0.0f;
    const bool s = (V >= V_spike);
    V = s ? V_reset : V;
    w = s ? (w + b) : w;
}

// Double-buffered UNR-deep prefetch loop (R4-proven structure).
#define RUN_BLOCKS(IPTR, OPTR, NBLK, ...) do {                                    \
    float bufA_[UNR], bufB_[UNR];                                                 \
    _Pragma("unroll") for (int k = 0; k < UNR; ++k) bufA_[k] = (IPTR)[k * Dn];    \
    for (int tb = 0; tb < (NBLK); tb += 2) {                                      \
        if (tb + 1 < (NBLK)) {                                                    \
            const float* pp_ = (IPTR) + (size_t)(tb + 1) * (UNR * Dn);            \
            _Pragma("unroll") for (int k = 0; k < UNR; ++k) bufB_[k] = pp_[k*Dn]; \
        }                                                                         \
        {                                                                         \
            float* oo_ = (OPTR) + (size_t)tb * (UNR * Dn);                        \
            _Pragma("unroll") for (int k = 0; k < UNR; ++k) {                     \
                const float i_t = bufA_[k];                                       \
                float* OSLOT = oo_ + (size_t)k * Dn; (void)OSLOT;                 \
                __VA_ARGS__;                                                      \
            }                                                                     \
        }                                                                         \
        if (tb + 2 < (NBLK)) {                                                    \
            const float* pp_ = (IPTR) + (size_t)(tb + 2) * (UNR * Dn);            \
            _Pragma("unroll") for (int k = 0; k < UNR; ++k) bufA_[k] = pp_[k*Dn]; \
        }                                                                         \
        if (tb + 1 < (NBLK)) {                                                    \
            float* oo_ = (OPTR) + (size_t)(tb + 1) * (UNR * Dn);                  \
            _Pragma("unroll") for (int k = 0; k < UNR; ++k) {                     \
                const float i_t = bufB_[k];                                       \
                float* OSLOT = oo_ + (size_t)k * Dn; (void)OSLOT;                 \
                __VA_ARGS__;                                                      \
            }                                                                     \
        }                                                                         \
    }                                                                             \
} while (0)

__launch_bounds__(128, 1)
__global__ void adex_kernel(const float* __restrict__ I,
                            const float* __restrict__ params,
                            float* __restrict__ out) {
    #pragma clang fp contract(off)

    const float tau_m   = params[0];
    const float E_L     = params[1];
    const float V_T     = params[2];
    const float Delta_T = params[3];
    const float R       = params[4];
    const float tau_w   = params[5];
    const float a       = params[6];
    const float b       = params[7];
    const float V_reset = params[8];
    const float V_spike = params[9];
    const float dt      = params[10];

    const int n = blockIdx.x * blockDim.x + threadIdx.x;
    if (n >= NEUR) return;
    const int bb = n >> 10;          // / Dn
    const int dd = n & (Dn - 1);     // % Dn

    const float* Ip = I   + (size_t)bb * (size_t)(Tn * Dn) + dd;
    float*       Op = out + (size_t)bb * (size_t)(Tn * Dn) + dd;

    const unsigned dtBits = __float_as_uint(Delta_T);
    const bool dtPow2 = ((dtBits & 0x7FFFFFu) == 0u) && Delta_T > 0.0f;
    const bool hot = (a == 0.0f) && (b == 0.0f) && (R == 1.0f) && dtPow2;

    float V = E_L;

    if (hot) {
        HP p;
        p.tau_m = tau_m;
        p.rTM   = 1.0f / tau_m;
        p.dt    = dt;
        p.Vs    = V_spike;
        p.Vrst  = V_reset;
        p.E_L   = E_L;
        p.V_T   = V_T;
        p.kdt   = (int)((dtBits >> 23) & 0xFFu) - 127;
        p.rDT   = 1.0f / Delta_T;            // exact pow2
        p.KH    = EXP_LOG2EF * p.rDT;        // exact exponent shift
        p.T1C   = V_reset - V_T;
        p.nC    = E_L - V_reset;

        float t1  = V - V_T;                  // == ref (V - V_T)
        float nEL = E_L - V;                  // == -(V - E_L) up to +-0 (absorbed)
        RUN_BLOCKS(Ip, Op, NB,
            { *OSLOT = hot_step(V, t1, nEL, i_t, p); });
    } else if (a == 0.0f && b == 0.0f) {
        RUN_BLOCKS(Ip, Op, NB,
            { float spk; step_simple(V, i_t, spk, E_L, V_T, Delta_T, R, tau_m,
                                     V_spike, V_reset, dt); *OSLOT = spk; });
    } else {
        float w = 0.0f;
        RUN_BLOCKS(Ip, Op, NB,
            { float spk; step_general(V, w, i_t, spk, E_L, V_T, Delta_T, R, tau_m,
                                      tau_w, a, b, V_spike, V_reset, dt); *OSLOT = spk; });
    }
}

extern "C" void kernel_launch(void* const* d_in, const int* in_sizes, int n_in,
                              void* d_out, int out_size, void* d_ws, size_t ws_size,
                              hipStream_t stream) {
    const float* I      = (const float*)d_in[0];
    const float* params = (const float*)d_in[1];
    float*       out    = (float*)d_out;

    dim3 block(128);
    dim3 grid(NEUR / 128);  // 256 blocks -> 1 per CU
    adex_kernel<<<grid, block, 0, stream>>>(I, params, out);
}